// Round 1
// baseline (441.968 us; speedup 1.0000x reference)
//
#include <hip/hip_runtime.h>
#include <math.h>
#include <float.h>

#define NB 4096
#define ND 256
#define NK 25
#define EPSF 1e-8f

// ---------------------------------------------------------------- sq[i] = ||f_i||^2
__global__ __launch_bounds__(64) void sq_kernel(const float* __restrict__ f,
                                                float* __restrict__ sq) {
    int row  = blockIdx.x;
    int lane = threadIdx.x;                      // 64 lanes, D/4 = 64 float4
    float4 v = ((const float4*)(f + (size_t)row * ND))[lane];
    float acc = v.x * v.x + v.y * v.y + v.z * v.z + v.w * v.w;
#pragma unroll
    for (int off = 32; off; off >>= 1) acc += __shfl_down(acc, off);
    if (lane == 0) sq[row] = acc;
}

// ---------------------------------------------------------------- dist_sq = max(sq_i+sq_j-2*F F^T, 0)
#define TILE 64
#define KT   32
__global__ __launch_bounds__(256) void dist_kernel(const float* __restrict__ f,
                                                   const float* __restrict__ sq,
                                                   float* __restrict__ dist) {
    __shared__ float As[TILE][KT + 1];
    __shared__ float Bs[TILE][KT + 1];
    int tb = blockIdx.x;
    int ti = (tb / (NB / TILE)) * TILE;
    int tj = (tb % (NB / TILE)) * TILE;
    int tid = threadIdx.x;
    int tx = tid % 16, ty = tid / 16;            // 16x16 threads, 4x4 micro-tile
    float acc[4][4] = {};

    for (int k0 = 0; k0 < ND; k0 += KT) {
#pragma unroll
        for (int l = 0; l < 2; ++l) {
            int idx4 = tid * 2 + l;              // 0..511
            int r  = idx4 >> 3;                  // row in tile
            int c4 = idx4 & 7;                   // float4 col
            float4 va = *(const float4*)(f + (size_t)(ti + r) * ND + k0 + c4 * 4);
            As[r][c4 * 4 + 0] = va.x; As[r][c4 * 4 + 1] = va.y;
            As[r][c4 * 4 + 2] = va.z; As[r][c4 * 4 + 3] = va.w;
            float4 vb = *(const float4*)(f + (size_t)(tj + r) * ND + k0 + c4 * 4);
            Bs[r][c4 * 4 + 0] = vb.x; Bs[r][c4 * 4 + 1] = vb.y;
            Bs[r][c4 * 4 + 2] = vb.z; Bs[r][c4 * 4 + 3] = vb.w;
        }
        __syncthreads();
#pragma unroll
        for (int kk = 0; kk < KT; ++kk) {
            float a[4], b[4];
#pragma unroll
            for (int u = 0; u < 4; ++u) a[u] = As[ty * 4 + u][kk];
#pragma unroll
            for (int u = 0; u < 4; ++u) b[u] = Bs[tx * 4 + u][kk];
#pragma unroll
            for (int u = 0; u < 4; ++u)
#pragma unroll
                for (int v = 0; v < 4; ++v) acc[u][v] += a[u] * b[v];
        }
        __syncthreads();
    }
#pragma unroll
    for (int u = 0; u < 4; ++u) {
        int i = ti + ty * 4 + u;
        float si = sq[i];
        float4 o;
        o.x = fmaxf(si + sq[tj + tx * 4 + 0] - 2.f * acc[u][0], 0.f);
        o.y = fmaxf(si + sq[tj + tx * 4 + 1] - 2.f * acc[u][1], 0.f);
        o.z = fmaxf(si + sq[tj + tx * 4 + 2] - 2.f * acc[u][2], 0.f);
        o.w = fmaxf(si + sq[tj + tx * 4 + 3] - 2.f * acc[u][3], 0.f);
        *(float4*)(dist + (size_t)i * NB + tj + tx * 4) = o;
    }
}

// ---------------------------------------------------------------- per-row top-25 smallest + sigma
__global__ __launch_bounds__(256) void topk_kernel(const float* __restrict__ dist,
                                                   int* __restrict__ idxk,
                                                   float* __restrict__ dk,
                                                   float* __restrict__ sigma) {
    int row = blockIdx.x;
    __shared__ float rowv[NB];                   // 16 KB
    __shared__ float redv[4];
    __shared__ int   redi[4];
    int tid = threadIdx.x;
    const float4* src = (const float4*)(dist + (size_t)row * NB);
    for (int t = tid; t < NB / 4; t += 256) {
        float4 v = src[t];
        rowv[t * 4 + 0] = v.x; rowv[t * 4 + 1] = v.y;
        rowv[t * 4 + 2] = v.z; rowv[t * 4 + 3] = v.w;
    }
    __syncthreads();
    float ssum = 0.f;
    for (int it = 0; it < NK; ++it) {
        float bv = FLT_MAX; int bi = NB;
        for (int t = tid; t < NB; t += 256) {
            float v = rowv[t];
            if (v < bv || (v == bv && t < bi)) { bv = v; bi = t; }
        }
#pragma unroll
        for (int off = 32; off; off >>= 1) {
            float ov = __shfl_down(bv, off);
            int   oi = __shfl_down(bi, off);
            if (ov < bv || (ov == bv && oi < bi)) { bv = ov; bi = oi; }
        }
        if ((tid & 63) == 0) { redv[tid >> 6] = bv; redi[tid >> 6] = bi; }
        __syncthreads();
        if (tid == 0) {
#pragma unroll
            for (int w = 1; w < 4; ++w)
                if (redv[w] < bv || (redv[w] == bv && redi[w] < bi)) { bv = redv[w]; bi = redi[w]; }
            idxk[row * NK + it] = bi;
            dk[row * NK + it]   = bv;
            rowv[bi] = FLT_MAX;
            ssum += sqrtf(bv + EPSF);
        }
        __syncthreads();
    }
    if (tid == 0) sigma[row] = ssum * (1.0f / NK);
}

// ---------------------------------------------------------------- sparse P rows (values at topk idx)
__global__ __launch_bounds__(64) void buildp_kernel(const int* __restrict__ idxk,
                                                    const float* __restrict__ dk,
                                                    const float* __restrict__ sigma,
                                                    const int* __restrict__ labels,
                                                    float* __restrict__ pval) {
    int row  = blockIdx.x;
    int lane = threadIdx.x;                      // one wave; lanes 0..24 active
    float w = 0.f;
    if (lane < NK) {
        int j = idxk[row * NK + lane];
        bool mut = false;
        for (int n = 0; n < NK; ++n) mut |= (idxk[j * NK + n] == row);
        bool dir = labels[row] <= labels[j];
        float sij = sigma[row] * sigma[j] + EPSF;
        w = (mut && dir) ? expf(-dk[row * NK + lane] / sij) : 0.f;
        if (j == row) w += 1.f;                  // + eye
    }
    float rs = w;
#pragma unroll
    for (int off = 32; off; off >>= 1) rs += __shfl_down(rs, off);
    rs = __shfl(rs, 0);
    if (lane < NK) pval[row * NK + lane] = w / (rs + EPSF);
}

// ---------------------------------------------------------------- init out
__global__ void init_kernel(float* __restrict__ out) { out[0] = 0.f; }

// ---------------------------------------------------------------- sparse 3-hop loss
__global__ __launch_bounds__(256) void loss_kernel(const float* __restrict__ scores,
                                                   const int* __restrict__ idxk,
                                                   const float* __restrict__ pval,
                                                   float* __restrict__ out) {
    int i = blockIdx.x;
    __shared__ float sh_s[NB];                   // 16 KB
    __shared__ float sh_p[NK];
    __shared__ int   sh_j[NK];
    __shared__ float red[4];
    int tid = threadIdx.x;
    for (int t = tid; t < NB / 4; t += 256) {
        float4 v = ((const float4*)scores)[t];
        sh_s[4 * t + 0] = v.x; sh_s[4 * t + 1] = v.y;
        sh_s[4 * t + 2] = v.z; sh_s[4 * t + 3] = v.w;
    }
    if (tid < NK) { sh_p[tid] = pval[i * NK + tid]; sh_j[tid] = idxk[i * NK + tid]; }
    __syncthreads();
    float si = sh_s[i];
    float acc = 0.f;
    // t = 1
    if (tid < NK) acc += sh_p[tid] * fmaxf(si - sh_s[sh_j[tid]], 0.f);
    // t = 2, 3
    for (int pair = tid; pair < NK * NK; pair += 256) {
        int m = pair / NK, n = pair % NK;
        int   j   = sh_j[m];
        float pij = sh_p[m];
        int   q   = idxk[j * NK + n];
        float pjn = pval[j * NK + n];
        float pp  = pij * pjn;
        acc += 0.5f * pp * fmaxf(si - sh_s[q], 0.f);
        const int*   qi = idxk + q * NK;
        const float* qp = pval + q * NK;
        float s3 = 0.f;
        for (int r = 0; r < NK; ++r)
            s3 += qp[r] * fmaxf(si - sh_s[qi[r]], 0.f);
        acc += (1.f / 3.f) * pp * s3;
    }
#pragma unroll
    for (int off = 32; off; off >>= 1) acc += __shfl_down(acc, off);
    if ((tid & 63) == 0) red[tid >> 6] = acc;
    __syncthreads();
    if (tid == 0) atomicAdd(out, (red[0] + red[1] + red[2] + red[3]) * (1.0f / NB));
}

// ---------------------------------------------------------------- launch
extern "C" void kernel_launch(void* const* d_in, const int* in_sizes, int n_in,
                              void* d_out, int out_size, void* d_ws, size_t ws_size,
                              hipStream_t stream) {
    const float* features = (const float*)d_in[0];
    const float* scores   = (const float*)d_in[1];
    const int*   labels   = (const int*)d_in[2];
    float* out = (float*)d_out;

    char* ws = (char*)d_ws;
    float* dist  = (float*)(ws);                                   // 64 MB
    float* sq    = (float*)(ws + (size_t)NB * NB * 4);             // 16 KB
    int*   idxk  = (int*)  (ws + (size_t)NB * NB * 4 + 16384);     // 400 KB
    float* dk    = (float*)(ws + (size_t)NB * NB * 4 + 16384 + 409600);
    float* sigma = (float*)(ws + (size_t)NB * NB * 4 + 16384 + 2 * 409600);
    float* pval  = (float*)(ws + (size_t)NB * NB * 4 + 2 * 16384 + 2 * 409600);

    init_kernel<<<1, 1, 0, stream>>>(out);
    sq_kernel<<<NB, 64, 0, stream>>>(features, sq);
    dist_kernel<<<(NB / TILE) * (NB / TILE), 256, 0, stream>>>(features, sq, dist);
    topk_kernel<<<NB, 256, 0, stream>>>(dist, idxk, dk, sigma);
    buildp_kernel<<<NB, 64, 0, stream>>>(idxk, dk, sigma, labels, pval);
    loss_kernel<<<NB, 256, 0, stream>>>(scores, idxk, pval, out);
}

// Round 2
// 301.798 us; speedup vs baseline: 1.4644x; 1.4644x over previous
//
#include <hip/hip_runtime.h>
#include <math.h>
#include <float.h>

#define NB 4096
#define ND 256
#define NK 25
#define EPSF 1e-8f
#define CAND_CAP 1024

// ---------------------------------------------------------------- sq[i] = ||f_i||^2
__global__ __launch_bounds__(64) void sq_kernel(const float* __restrict__ f,
                                                float* __restrict__ sq) {
    int row  = blockIdx.x;
    int lane = threadIdx.x;                      // 64 lanes, D/4 = 64 float4
    float4 v = ((const float4*)(f + (size_t)row * ND))[lane];
    float acc = v.x * v.x + v.y * v.y + v.z * v.z + v.w * v.w;
#pragma unroll
    for (int off = 32; off; off >>= 1) acc += __shfl_down(acc, off);
    if (lane == 0) sq[row] = acc;
}

// ---------------------------------------------------------------- dist_sq = max(sq_i+sq_j-2*F F^T, 0)
#define TILE 64
#define KT   32
__global__ __launch_bounds__(256) void dist_kernel(const float* __restrict__ f,
                                                   const float* __restrict__ sq,
                                                   float* __restrict__ dist) {
    __shared__ float As[TILE][KT + 1];
    __shared__ float Bs[TILE][KT + 1];
    int tb = blockIdx.x;
    int ti = (tb / (NB / TILE)) * TILE;
    int tj = (tb % (NB / TILE)) * TILE;
    int tid = threadIdx.x;
    int tx = tid % 16, ty = tid / 16;            // 16x16 threads, 4x4 micro-tile
    float acc[4][4] = {};

    for (int k0 = 0; k0 < ND; k0 += KT) {
#pragma unroll
        for (int l = 0; l < 2; ++l) {
            int idx4 = tid * 2 + l;              // 0..511
            int r  = idx4 >> 3;                  // row in tile
            int c4 = idx4 & 7;                   // float4 col
            float4 va = *(const float4*)(f + (size_t)(ti + r) * ND + k0 + c4 * 4);
            As[r][c4 * 4 + 0] = va.x; As[r][c4 * 4 + 1] = va.y;
            As[r][c4 * 4 + 2] = va.z; As[r][c4 * 4 + 3] = va.w;
            float4 vb = *(const float4*)(f + (size_t)(tj + r) * ND + k0 + c4 * 4);
            Bs[r][c4 * 4 + 0] = vb.x; Bs[r][c4 * 4 + 1] = vb.y;
            Bs[r][c4 * 4 + 2] = vb.z; Bs[r][c4 * 4 + 3] = vb.w;
        }
        __syncthreads();
#pragma unroll
        for (int kk = 0; kk < KT; ++kk) {
            float a[4], b[4];
#pragma unroll
            for (int u = 0; u < 4; ++u) a[u] = As[ty * 4 + u][kk];
#pragma unroll
            for (int u = 0; u < 4; ++u) b[u] = Bs[tx * 4 + u][kk];
#pragma unroll
            for (int u = 0; u < 4; ++u)
#pragma unroll
                for (int v = 0; v < 4; ++v) acc[u][v] += a[u] * b[v];
        }
        __syncthreads();
    }
#pragma unroll
    for (int u = 0; u < 4; ++u) {
        int i = ti + ty * 4 + u;
        float si = sq[i];
        float4 o;
        o.x = fmaxf(si + sq[tj + tx * 4 + 0] - 2.f * acc[u][0], 0.f);
        o.y = fmaxf(si + sq[tj + tx * 4 + 1] - 2.f * acc[u][1], 0.f);
        o.z = fmaxf(si + sq[tj + tx * 4 + 2] - 2.f * acc[u][2], 0.f);
        o.w = fmaxf(si + sq[tj + tx * 4 + 3] - 2.f * acc[u][3], 0.f);
        *(float4*)(dist + (size_t)i * NB + tj + tx * 4) = o;
    }
}

// ---------------------------------------------------------------- per-row top-25 via bisection-count select
// Row lives in 16 VGPRs/thread. Binary search threshold on the uint bit
// pattern (order-preserving for floats >= 0) until count(<T) in [NK,192],
// compact candidates to LDS, exact 25-way select on one wave with
// (value,index) tie-break == jax.lax.top_k selected set.
__global__ __launch_bounds__(256) void topk2_kernel(const float* __restrict__ dist,
                                                    int* __restrict__ idxk,
                                                    float* __restrict__ dk,
                                                    float* __restrict__ sigma) {
    int row = blockIdx.x;
    int tid = threadIdx.x;
    __shared__ float cand_val[CAND_CAP];
    __shared__ int   cand_idx[CAND_CAP];
    __shared__ int   red[4];
    __shared__ float redf[4];
    __shared__ int   s_cnt;

    // load this thread's 16 row elements (coalesced float4)
    float v[16];
    const float4* src = (const float4*)(dist + (size_t)row * NB);
#pragma unroll
    for (int w = 0; w < 4; ++w) {
        float4 q = src[w * 256 + tid];
        v[w * 4 + 0] = q.x; v[w * 4 + 1] = q.y;
        v[w * 4 + 2] = q.z; v[w * 4 + 3] = q.w;
    }

    // block max (upper bound for bisection)
    float mx = v[0];
#pragma unroll
    for (int e = 1; e < 16; ++e) mx = fmaxf(mx, v[e]);
#pragma unroll
    for (int off = 32; off; off >>= 1) mx = fmaxf(mx, __shfl_down(mx, off));
    if ((tid & 63) == 0) redf[tid >> 6] = mx;
    __syncthreads();
    mx = fmaxf(fmaxf(redf[0], redf[1]), fmaxf(redf[2], redf[3]));

    // uint bisection: invariant count(<lo) < NK <= count(<hi)
    unsigned lo = 0u, hi = __float_as_uint(mx) + 1u;
    int cnt_hi = NB;
    for (int it = 0; it < 34; ++it) {
        if (cnt_hi <= 192 || hi <= lo + 1u) break;
        unsigned mid = (lo + hi) >> 1;
        float T = __uint_as_float(mid);
        int c = 0;
#pragma unroll
        for (int e = 0; e < 16; ++e) c += (v[e] < T) ? 1 : 0;
#pragma unroll
        for (int off = 32; off; off >>= 1) c += __shfl_down(c, off);
        __syncthreads();                       // red[] reuse hazard
        if ((tid & 63) == 0) red[tid >> 6] = c;
        __syncthreads();
        c = red[0] + red[1] + red[2] + red[3]; // uniform across block
        if (c >= NK) { hi = mid; cnt_hi = c; } else { lo = mid; }
    }

    // compact candidates < T_hi
    float Thi = __uint_as_float(hi);
    if (tid == 0) s_cnt = 0;
    __syncthreads();
#pragma unroll
    for (int w = 0; w < 4; ++w)
#pragma unroll
        for (int c4 = 0; c4 < 4; ++c4) {
            int e = w * 4 + c4;
            if (v[e] < Thi) {
                int p = atomicAdd(&s_cnt, 1);
                if (p < CAND_CAP) {
                    cand_val[p] = v[e];
                    cand_idx[p] = (w * 256 + tid) * 4 + c4;
                }
            }
        }
    __syncthreads();
    int cnt = min(s_cnt, CAND_CAP);

    // exact select of NK smallest on wave 0, (value,index) lexicographic
    if (tid < 64) {
        float ssum = 0.f;
        for (int it = 0; it < NK; ++it) {
            float bv = FLT_MAX; int bi = NB; int bp = -1;
            for (int r = tid; r < cnt; r += 64) {
                float cv = cand_val[r]; int ci = cand_idx[r];
                if (cv < bv || (cv == bv && ci < bi)) { bv = cv; bi = ci; bp = r; }
            }
#pragma unroll
            for (int off = 32; off; off >>= 1) {
                float ov = __shfl_down(bv, off);
                int   oi = __shfl_down(bi, off);
                int   op = __shfl_down(bp, off);
                if (ov < bv || (ov == bv && oi < bi)) { bv = ov; bi = oi; bp = op; }
            }
            bp = __shfl(bp, 0);
            bv = __shfl(bv, 0);
            bi = __shfl(bi, 0);
            if (tid == 0) {
                idxk[row * NK + it] = bi;
                dk[row * NK + it]   = bv;
                ssum += sqrtf(bv + EPSF);
                cand_val[bp] = FLT_MAX;        // mark used
            }
        }
        if (tid == 0) sigma[row] = ssum * (1.0f / NK);
    }
}

// ---------------------------------------------------------------- sparse P rows (values at topk idx)
__global__ __launch_bounds__(64) void buildp_kernel(const int* __restrict__ idxk,
                                                    const float* __restrict__ dk,
                                                    const float* __restrict__ sigma,
                                                    const int* __restrict__ labels,
                                                    float* __restrict__ pval) {
    int row  = blockIdx.x;
    int lane = threadIdx.x;                      // one wave; lanes 0..24 active
    float w = 0.f;
    if (lane < NK) {
        int j = idxk[row * NK + lane];
        bool mut = false;
        for (int n = 0; n < NK; ++n) mut |= (idxk[j * NK + n] == row);
        bool dir = labels[row] <= labels[j];
        float sij = sigma[row] * sigma[j] + EPSF;
        w = (mut && dir) ? expf(-dk[row * NK + lane] / sij) : 0.f;
        if (j == row) w += 1.f;                  // + eye
    }
    float rs = w;
#pragma unroll
    for (int off = 32; off; off >>= 1) rs += __shfl_down(rs, off);
    rs = __shfl(rs, 0);
    if (lane < NK) pval[row * NK + lane] = w / (rs + EPSF);
}

// ---------------------------------------------------------------- init out
__global__ void init_kernel(float* __restrict__ out) { out[0] = 0.f; }

// ---------------------------------------------------------------- sparse 3-hop loss
__global__ __launch_bounds__(256) void loss_kernel(const float* __restrict__ scores,
                                                   const int* __restrict__ idxk,
                                                   const float* __restrict__ pval,
                                                   float* __restrict__ out) {
    int i = blockIdx.x;
    __shared__ float sh_s[NB];                   // 16 KB
    __shared__ float sh_p[NK];
    __shared__ int   sh_j[NK];
    __shared__ float red[4];
    int tid = threadIdx.x;
    for (int t = tid; t < NB / 4; t += 256) {
        float4 v = ((const float4*)scores)[t];
        sh_s[4 * t + 0] = v.x; sh_s[4 * t + 1] = v.y;
        sh_s[4 * t + 2] = v.z; sh_s[4 * t + 3] = v.w;
    }
    if (tid < NK) { sh_p[tid] = pval[i * NK + tid]; sh_j[tid] = idxk[i * NK + tid]; }
    __syncthreads();
    float si = sh_s[i];
    float acc = 0.f;
    // t = 1
    if (tid < NK) acc += sh_p[tid] * fmaxf(si - sh_s[sh_j[tid]], 0.f);
    // t = 2, 3
    for (int pair = tid; pair < NK * NK; pair += 256) {
        int m = pair / NK, n = pair % NK;
        int   j   = sh_j[m];
        float pij = sh_p[m];
        int   q   = idxk[j * NK + n];
        float pjn = pval[j * NK + n];
        float pp  = pij * pjn;
        acc += 0.5f * pp * fmaxf(si - sh_s[q], 0.f);
        const int*   qi = idxk + q * NK;
        const float* qp = pval + q * NK;
        float s3 = 0.f;
        for (int r = 0; r < NK; ++r)
            s3 += qp[r] * fmaxf(si - sh_s[qi[r]], 0.f);
        acc += (1.f / 3.f) * pp * s3;
    }
#pragma unroll
    for (int off = 32; off; off >>= 1) acc += __shfl_down(acc, off);
    if ((tid & 63) == 0) red[tid >> 6] = acc;
    __syncthreads();
    if (tid == 0) atomicAdd(out, (red[0] + red[1] + red[2] + red[3]) * (1.0f / NB));
}

// ---------------------------------------------------------------- launch
extern "C" void kernel_launch(void* const* d_in, const int* in_sizes, int n_in,
                              void* d_out, int out_size, void* d_ws, size_t ws_size,
                              hipStream_t stream) {
    const float* features = (const float*)d_in[0];
    const float* scores   = (const float*)d_in[1];
    const int*   labels   = (const int*)d_in[2];
    float* out = (float*)d_out;

    char* ws = (char*)d_ws;
    float* dist  = (float*)(ws);                                   // 64 MB
    float* sq    = (float*)(ws + (size_t)NB * NB * 4);             // 16 KB
    int*   idxk  = (int*)  (ws + (size_t)NB * NB * 4 + 16384);     // 400 KB
    float* dk    = (float*)(ws + (size_t)NB * NB * 4 + 16384 + 409600);
    float* sigma = (float*)(ws + (size_t)NB * NB * 4 + 16384 + 2 * 409600);
    float* pval  = (float*)(ws + (size_t)NB * NB * 4 + 2 * 16384 + 2 * 409600);

    init_kernel<<<1, 1, 0, stream>>>(out);
    sq_kernel<<<NB, 64, 0, stream>>>(features, sq);
    dist_kernel<<<(NB / TILE) * (NB / TILE), 256, 0, stream>>>(features, sq, dist);
    topk2_kernel<<<NB, 256, 0, stream>>>(dist, idxk, dk, sigma);
    buildp_kernel<<<NB, 64, 0, stream>>>(idxk, dk, sigma, labels, pval);
    loss_kernel<<<NB, 256, 0, stream>>>(scores, idxk, pval, out);
}

// Round 3
// 188.396 us; speedup vs baseline: 2.3460x; 1.6019x over previous
//
#include <hip/hip_runtime.h>
#include <math.h>
#include <float.h>

#define NB 4096
#define ND 256
#define NK 25
#define EPSF 1e-8f
#define CAND_CAP 1024

typedef __attribute__((ext_vector_type(8))) short bf16x8;
typedef __attribute__((ext_vector_type(4))) float f32x4;

// global -> LDS direct 16B load (CK-style addrspace casts via uintptr_t)
#define GLD_LDS16(gp, lp)                                                   \
    __builtin_amdgcn_global_load_lds(                                       \
        (const __attribute__((address_space(1))) void*)(uintptr_t)(gp),     \
        (__attribute__((address_space(3))) void*)(uint32_t)(uintptr_t)(lp), \
        16, 0, 0)

__device__ inline short f2bf(float x) {          // RNE float->bf16 bits
    unsigned u = __float_as_uint(x);
    return (short)((u + 0x7FFF + ((u >> 16) & 1)) >> 16);
}
__device__ inline float bf2f(short s) {
    return __uint_as_float(((unsigned)(unsigned short)s) << 16);
}

// ---------------------------------------------------------------- prep: hi/lo bf16 split + ||f||^2
// fhl[row][0..255] = hi, fhl[row][256..511] = lo
__global__ __launch_bounds__(64) void prep_kernel(const float* __restrict__ f,
                                                  short* __restrict__ fhl,
                                                  float* __restrict__ sq) {
    int row  = blockIdx.x;
    int lane = threadIdx.x;
    float4 v = ((const float4*)(f + (size_t)row * ND))[lane];
    float acc = v.x * v.x + v.y * v.y + v.z * v.z + v.w * v.w;
    float vv[4] = {v.x, v.y, v.z, v.w};
    short h[4], l[4];
#pragma unroll
    for (int e = 0; e < 4; ++e) {
        h[e] = f2bf(vv[e]);
        l[e] = f2bf(vv[e] - bf2f(h[e]));
    }
    short4 hv = make_short4(h[0], h[1], h[2], h[3]);
    short4 lv = make_short4(l[0], l[1], l[2], l[3]);
    *(short4*)(fhl + (size_t)row * 512 + lane * 4)       = hv;
    *(short4*)(fhl + (size_t)row * 512 + 256 + lane * 4) = lv;
#pragma unroll
    for (int off = 32; off; off >>= 1) acc += __shfl_down(acc, off);
    if (lane == 0) sq[row] = acc;
}

// ---------------------------------------------------------------- MFMA Gram + dist epilogue
// C = A.B^T over K=768 virtual columns: A k->[h,h,l], B k->[h,l,h].
// dist[i][j] = max(sq_i + sq_j - 2*dot, 0)
#define BM 128
#define BK 64
__global__ __launch_bounds__(256) void gram_kernel(const short* __restrict__ fhl,
                                                   const float* __restrict__ sq,
                                                   float* __restrict__ dist) {
    __shared__ __align__(16) short As[BM * BK];
    __shared__ __align__(16) short Bs[BM * BK];
    int b   = blockIdx.x;
    int ti  = (b >> 5) * BM;
    int tj  = (b & 31) * BM;
    int tid = threadIdx.x;
    int w = tid >> 6, lane = tid & 63;
    int wr = w >> 1, wc = w & 1;                 // wave's 64x64 quadrant
    int fr = lane & 15, fq = lane >> 4;          // fragment row/col split

    f32x4 acc[4][4];
#pragma unroll
    for (int m = 0; m < 4; ++m)
#pragma unroll
        for (int n = 0; n < 4; ++n) acc[m][n] = (f32x4){0.f, 0.f, 0.f, 0.f};

    int srow = lane >> 3;                        // staging row within 8-row chunk
    int scol = (lane & 7) * 8;                   // staging col (bf16 elems)

    for (int s = 0; s < 12; ++s) {
        int k0 = s * 64;
        int kA = (k0 < 512) ? (k0 & 255) : (k0 - 256);   // h,h,l
        int kB = (k0 < 512) ? k0 : (k0 - 512);           // h,l,h
#pragma unroll
        for (int i = 0; i < 4; ++i) {
            int c   = 4 * w + i;                 // 1KB wave-chunk 0..15
            int row = c * 8 + srow;
            GLD_LDS16(fhl + (size_t)(ti + row) * 512 + kA + scol, As + c * 512);
            GLD_LDS16(fhl + (size_t)(tj + row) * 512 + kB + scol, Bs + c * 512);
        }
        __syncthreads();                         // drains vmcnt before LDS reads
#pragma unroll
        for (int kk = 0; kk < 2; ++kk) {
            bf16x8 af[4], bfr[4];
#pragma unroll
            for (int m = 0; m < 4; ++m)
                af[m] = *(const bf16x8*)(As + (wr * 64 + m * 16 + fr) * 64 + kk * 32 + fq * 8);
#pragma unroll
            for (int n = 0; n < 4; ++n)
                bfr[n] = *(const bf16x8*)(Bs + (wc * 64 + n * 16 + fr) * 64 + kk * 32 + fq * 8);
#pragma unroll
            for (int m = 0; m < 4; ++m)
#pragma unroll
                for (int n = 0; n < 4; ++n)
                    acc[m][n] = __builtin_amdgcn_mfma_f32_16x16x32_bf16(af[m], bfr[n], acc[m][n], 0, 0, 0);
        }
        __syncthreads();
    }

    // epilogue: C/D layout col=lane&15, row=(lane>>4)*4+j  [m89]
#pragma unroll
    for (int m = 0; m < 4; ++m) {
#pragma unroll
        for (int j = 0; j < 4; ++j) {
            int gi = ti + wr * 64 + m * 16 + fq * 4 + j;
            float si = sq[gi];
            float* drow = dist + (size_t)gi * NB + tj + wc * 64;
#pragma unroll
            for (int n = 0; n < 4; ++n) {
                float d = si + sq[tj + wc * 64 + n * 16 + fr] - 2.f * acc[m][n][j];
                drow[n * 16 + fr] = fmaxf(d, 0.f);
            }
        }
    }
}

// ---------------------------------------------------------------- per-row top-25 via bisection-count select
__global__ __launch_bounds__(256) void topk2_kernel(const float* __restrict__ dist,
                                                    int* __restrict__ idxk,
                                                    float* __restrict__ dk,
                                                    float* __restrict__ sigma) {
    int row = blockIdx.x;
    int tid = threadIdx.x;
    __shared__ float cand_val[CAND_CAP];
    __shared__ int   cand_idx[CAND_CAP];
    __shared__ int   red[4];
    __shared__ float redf[4];
    __shared__ int   s_cnt;

    float v[16];
    const float4* src = (const float4*)(dist + (size_t)row * NB);
#pragma unroll
    for (int w = 0; w < 4; ++w) {
        float4 q = src[w * 256 + tid];
        v[w * 4 + 0] = q.x; v[w * 4 + 1] = q.y;
        v[w * 4 + 2] = q.z; v[w * 4 + 3] = q.w;
    }

    float mx = v[0];
#pragma unroll
    for (int e = 1; e < 16; ++e) mx = fmaxf(mx, v[e]);
#pragma unroll
    for (int off = 32; off; off >>= 1) mx = fmaxf(mx, __shfl_down(mx, off));
    if ((tid & 63) == 0) redf[tid >> 6] = mx;
    __syncthreads();
    mx = fmaxf(fmaxf(redf[0], redf[1]), fmaxf(redf[2], redf[3]));

    unsigned lo = 0u, hi = __float_as_uint(mx) + 1u;
    int cnt_hi = NB;
    for (int it = 0; it < 34; ++it) {
        if (cnt_hi <= 192 || hi <= lo + 1u) break;
        unsigned mid = (lo + hi) >> 1;
        float T = __uint_as_float(mid);
        int c = 0;
#pragma unroll
        for (int e = 0; e < 16; ++e) c += (v[e] < T) ? 1 : 0;
#pragma unroll
        for (int off = 32; off; off >>= 1) c += __shfl_down(c, off);
        __syncthreads();
        if ((tid & 63) == 0) red[tid >> 6] = c;
        __syncthreads();
        c = red[0] + red[1] + red[2] + red[3];
        if (c >= NK) { hi = mid; cnt_hi = c; } else { lo = mid; }
    }

    float Thi = __uint_as_float(hi);
    if (tid == 0) s_cnt = 0;
    __syncthreads();
#pragma unroll
    for (int w = 0; w < 4; ++w)
#pragma unroll
        for (int c4 = 0; c4 < 4; ++c4) {
            int e = w * 4 + c4;
            if (v[e] < Thi) {
                int p = atomicAdd(&s_cnt, 1);
                if (p < CAND_CAP) {
                    cand_val[p] = v[e];
                    cand_idx[p] = (w * 256 + tid) * 4 + c4;
                }
            }
        }
    __syncthreads();
    int cnt = min(s_cnt, CAND_CAP);

    if (tid < 64) {
        float ssum = 0.f;
        for (int it = 0; it < NK; ++it) {
            float bv = FLT_MAX; int bi = NB; int bp = -1;
            for (int r = tid; r < cnt; r += 64) {
                float cv = cand_val[r]; int ci = cand_idx[r];
                if (cv < bv || (cv == bv && ci < bi)) { bv = cv; bi = ci; bp = r; }
            }
#pragma unroll
            for (int off = 32; off; off >>= 1) {
                float ov = __shfl_down(bv, off);
                int   oi = __shfl_down(bi, off);
                int   op = __shfl_down(bp, off);
                if (ov < bv || (ov == bv && oi < bi)) { bv = ov; bi = oi; bp = op; }
            }
            bp = __shfl(bp, 0);
            bv = __shfl(bv, 0);
            bi = __shfl(bi, 0);
            if (tid == 0) {
                idxk[row * NK + it] = bi;
                dk[row * NK + it]   = bv;
                ssum += sqrtf(bv + EPSF);
                cand_val[bp] = FLT_MAX;
            }
        }
        if (tid == 0) sigma[row] = ssum * (1.0f / NK);
    }
}

// ---------------------------------------------------------------- sparse P rows
__global__ __launch_bounds__(64) void buildp_kernel(const int* __restrict__ idxk,
                                                    const float* __restrict__ dk,
                                                    const float* __restrict__ sigma,
                                                    const int* __restrict__ labels,
                                                    float* __restrict__ pval) {
    int row  = blockIdx.x;
    int lane = threadIdx.x;
    float w = 0.f;
    if (lane < NK) {
        int j = idxk[row * NK + lane];
        bool mut = false;
        for (int n = 0; n < NK; ++n) mut |= (idxk[j * NK + n] == row);
        bool dir = labels[row] <= labels[j];
        float sij = sigma[row] * sigma[j] + EPSF;
        w = (mut && dir) ? expf(-dk[row * NK + lane] / sij) : 0.f;
        if (j == row) w += 1.f;
    }
    float rs = w;
#pragma unroll
    for (int off = 32; off; off >>= 1) rs += __shfl_down(rs, off);
    rs = __shfl(rs, 0);
    if (lane < NK) pval[row * NK + lane] = w / (rs + EPSF);
}

// ---------------------------------------------------------------- init out
__global__ void init_kernel(float* __restrict__ out) { out[0] = 0.f; }

// ---------------------------------------------------------------- sparse 3-hop loss
__global__ __launch_bounds__(256) void loss_kernel(const float* __restrict__ scores,
                                                   const int* __restrict__ idxk,
                                                   const float* __restrict__ pval,
                                                   float* __restrict__ out) {
    int i = blockIdx.x;
    __shared__ float sh_s[NB];
    __shared__ float sh_p[NK];
    __shared__ int   sh_j[NK];
    __shared__ float red[4];
    int tid = threadIdx.x;
    for (int t = tid; t < NB / 4; t += 256) {
        float4 v = ((const float4*)scores)[t];
        sh_s[4 * t + 0] = v.x; sh_s[4 * t + 1] = v.y;
        sh_s[4 * t + 2] = v.z; sh_s[4 * t + 3] = v.w;
    }
    if (tid < NK) { sh_p[tid] = pval[i * NK + tid]; sh_j[tid] = idxk[i * NK + tid]; }
    __syncthreads();
    float si = sh_s[i];
    float acc = 0.f;
    if (tid < NK) acc += sh_p[tid] * fmaxf(si - sh_s[sh_j[tid]], 0.f);
    for (int pair = tid; pair < NK * NK; pair += 256) {
        int m = pair / NK, n = pair % NK;
        int   j   = sh_j[m];
        float pij = sh_p[m];
        int   q   = idxk[j * NK + n];
        float pjn = pval[j * NK + n];
        float pp  = pij * pjn;
        acc += 0.5f * pp * fmaxf(si - sh_s[q], 0.f);
        const int*   qi = idxk + q * NK;
        const float* qp = pval + q * NK;
        float s3 = 0.f;
        for (int r = 0; r < NK; ++r)
            s3 += qp[r] * fmaxf(si - sh_s[qi[r]], 0.f);
        acc += (1.f / 3.f) * pp * s3;
    }
#pragma unroll
    for (int off = 32; off; off >>= 1) acc += __shfl_down(acc, off);
    if ((tid & 63) == 0) red[tid >> 6] = acc;
    __syncthreads();
    if (tid == 0) atomicAdd(out, (red[0] + red[1] + red[2] + red[3]) * (1.0f / NB));
}

// ---------------------------------------------------------------- launch
extern "C" void kernel_launch(void* const* d_in, const int* in_sizes, int n_in,
                              void* d_out, int out_size, void* d_ws, size_t ws_size,
                              hipStream_t stream) {
    const float* features = (const float*)d_in[0];
    const float* scores   = (const float*)d_in[1];
    const int*   labels   = (const int*)d_in[2];
    float* out = (float*)d_out;

    char* ws = (char*)d_ws;
    size_t off = 0;
    float* dist  = (float*)(ws + off); off += (size_t)NB * NB * 4;   // 64 MB
    short* fhl   = (short*)(ws + off); off += (size_t)NB * 512 * 2;  // 4 MB
    float* sq    = (float*)(ws + off); off += (size_t)NB * 4;
    int*   idxk  = (int*)  (ws + off); off += (size_t)NB * NK * 4;
    float* dk    = (float*)(ws + off); off += (size_t)NB * NK * 4;
    float* sigma = (float*)(ws + off); off += (size_t)NB * 4;
    float* pval  = (float*)(ws + off);

    init_kernel<<<1, 1, 0, stream>>>(out);
    prep_kernel<<<NB, 64, 0, stream>>>(features, fhl, sq);
    gram_kernel<<<(NB / BM) * (NB / BM), 256, 0, stream>>>(fhl, sq, dist);
    topk2_kernel<<<NB, 256, 0, stream>>>(dist, idxk, dk, sigma);
    buildp_kernel<<<NB, 64, 0, stream>>>(idxk, dk, sigma, labels, pval);
    loss_kernel<<<NB, 256, 0, stream>>>(scores, idxk, pval, out);
}

// Round 4
// 178.631 us; speedup vs baseline: 2.4742x; 1.0547x over previous
//
#include <hip/hip_runtime.h>
#include <math.h>
#include <float.h>

#define NB 4096
#define ND 256
#define NK 25
#define EPSF 1e-8f
#define CAP 256          // per-wave candidate capacity
#define CTGT 160         // bisection target count

typedef __attribute__((ext_vector_type(8))) short bf16x8;
typedef __attribute__((ext_vector_type(4))) float f32x4;

#define GLD_LDS16(gp, lp)                                                   \
    __builtin_amdgcn_global_load_lds(                                       \
        (const __attribute__((address_space(1))) void*)(uintptr_t)(gp),     \
        (__attribute__((address_space(3))) void*)(uint32_t)(uintptr_t)(lp), \
        16, 0, 0)

__device__ inline short f2bf(float x) {
    unsigned u = __float_as_uint(x);
    return (short)((u + 0x7FFF + ((u >> 16) & 1)) >> 16);
}
__device__ inline float bf2f(short s) {
    return __uint_as_float(((unsigned)(unsigned short)s) << 16);
}

// ---------------------------------------------------------------- prep: hi/lo bf16 split + ||f||^2
__global__ __launch_bounds__(64) void prep_kernel(const float* __restrict__ f,
                                                  short* __restrict__ fhl,
                                                  float* __restrict__ sq) {
    int row  = blockIdx.x;
    int lane = threadIdx.x;
    float4 v = ((const float4*)(f + (size_t)row * ND))[lane];
    float acc = v.x * v.x + v.y * v.y + v.z * v.z + v.w * v.w;
    float vv[4] = {v.x, v.y, v.z, v.w};
    short h[4], l[4];
#pragma unroll
    for (int e = 0; e < 4; ++e) {
        h[e] = f2bf(vv[e]);
        l[e] = f2bf(vv[e] - bf2f(h[e]));
    }
    *(short4*)(fhl + (size_t)row * 512 + lane * 4)       = make_short4(h[0], h[1], h[2], h[3]);
    *(short4*)(fhl + (size_t)row * 512 + 256 + lane * 4) = make_short4(l[0], l[1], l[2], l[3]);
#pragma unroll
    for (int off = 32; off; off >>= 1) acc += __shfl_down(acc, off);
    if (lane == 0) sq[row] = acc;
}

// ---------------------------------------------------------------- MFMA Gram + dist epilogue
#define BM 128
#define BK 64
__global__ __launch_bounds__(256) void gram_kernel(const short* __restrict__ fhl,
                                                   const float* __restrict__ sq,
                                                   float* __restrict__ dist) {
    __shared__ __align__(16) short As[BM * BK];
    __shared__ __align__(16) short Bs[BM * BK];
    int b   = blockIdx.x;
    int ti  = (b >> 5) * BM;
    int tj  = (b & 31) * BM;
    int tid = threadIdx.x;
    int w = tid >> 6, lane = tid & 63;
    int wr = w >> 1, wc = w & 1;
    int fr = lane & 15, fq = lane >> 4;

    f32x4 acc[4][4];
#pragma unroll
    for (int m = 0; m < 4; ++m)
#pragma unroll
        for (int n = 0; n < 4; ++n) acc[m][n] = (f32x4){0.f, 0.f, 0.f, 0.f};

    int srow = lane >> 3;
    int scol = (lane & 7) * 8;

    for (int s = 0; s < 12; ++s) {
        int k0 = s * 64;
        int kA = (k0 < 512) ? (k0 & 255) : (k0 - 256);   // h,h,l
        int kB = (k0 < 512) ? k0 : (k0 - 512);           // h,l,h
#pragma unroll
        for (int i = 0; i < 4; ++i) {
            int c   = 4 * w + i;
            int row = c * 8 + srow;
            GLD_LDS16(fhl + (size_t)(ti + row) * 512 + kA + scol, As + c * 512);
            GLD_LDS16(fhl + (size_t)(tj + row) * 512 + kB + scol, Bs + c * 512);
        }
        __syncthreads();
#pragma unroll
        for (int kk = 0; kk < 2; ++kk) {
            bf16x8 af[4], bfr[4];
#pragma unroll
            for (int m = 0; m < 4; ++m)
                af[m] = *(const bf16x8*)(As + (wr * 64 + m * 16 + fr) * 64 + kk * 32 + fq * 8);
#pragma unroll
            for (int n = 0; n < 4; ++n)
                bfr[n] = *(const bf16x8*)(Bs + (wc * 64 + n * 16 + fr) * 64 + kk * 32 + fq * 8);
#pragma unroll
            for (int m = 0; m < 4; ++m)
#pragma unroll
                for (int n = 0; n < 4; ++n)
                    acc[m][n] = __builtin_amdgcn_mfma_f32_16x16x32_bf16(af[m], bfr[n], acc[m][n], 0, 0, 0);
        }
        __syncthreads();
    }

#pragma unroll
    for (int m = 0; m < 4; ++m) {
#pragma unroll
        for (int j = 0; j < 4; ++j) {
            int gi = ti + wr * 64 + m * 16 + fq * 4 + j;
            float si = sq[gi];
            float* drow = dist + (size_t)gi * NB + tj + wc * 64;
#pragma unroll
            for (int n = 0; n < 4; ++n) {
                float d = si + sq[tj + wc * 64 + n * 16 + fr] - 2.f * acc[m][n][j];
                drow[n * 16 + fr] = fmaxf(d, 0.f);
            }
        }
    }
}

// ---------------------------------------------------------------- wave-per-row top-25 (no barriers)
__global__ __launch_bounds__(256) void topk3_kernel(const float* __restrict__ dist,
                                                    int* __restrict__ idxk,
                                                    float* __restrict__ dk,
                                                    float* __restrict__ sigma) {
    int wid  = threadIdx.x >> 6;
    int lane = threadIdx.x & 63;
    int row  = blockIdx.x * 4 + wid;
    __shared__ float cval[4][CAP];
    __shared__ int   cidx[4][CAP];

    // 64 values/lane: element (c*64+lane)*4+e
    float v[64];
    const float4* src = (const float4*)(dist + (size_t)row * NB);
#pragma unroll
    for (int c = 0; c < 16; ++c) {
        float4 q = src[c * 64 + lane];
        v[c * 4 + 0] = q.x; v[c * 4 + 1] = q.y;
        v[c * 4 + 2] = q.z; v[c * 4 + 3] = q.w;
    }

    // wave max (all lanes get result)
    float mx = v[0];
#pragma unroll
    for (int e = 1; e < 64; ++e) mx = fmaxf(mx, v[e]);
#pragma unroll
    for (int off = 32; off; off >>= 1) mx = fmaxf(mx, __shfl_xor(mx, off));

    // uint bisection on bit pattern (order-preserving, all values >= 0)
    unsigned lo = 0u, hi = __float_as_uint(mx) + 1u;
    int cnt_hi = NB;
    for (int it = 0; it < 40; ++it) {
        if (cnt_hi <= CTGT || hi <= lo + 1u) break;
        unsigned mid = (lo + hi) >> 1;
        float T = __uint_as_float(mid);
        int c = 0;
#pragma unroll
        for (int e = 0; e < 64; ++e) c += (v[e] < T) ? 1 : 0;
#pragma unroll
        for (int off = 32; off; off >>= 1) c += __shfl_xor(c, off);
        if (c >= NK) { hi = mid; cnt_hi = c; } else { lo = mid; }
    }

    // ballot/popc compaction of candidates < T_hi into this wave's LDS slab
    float Thi = __uint_as_float(hi);
    unsigned long long ltmask = (1ull << lane) - 1ull;
    int cnt = 0;
#pragma unroll
    for (int e = 0; e < 64; ++e) {
        bool p = (v[e] < Thi);
        unsigned long long m = __ballot(p);
        if (p) {
            int pos = cnt + __popcll(m & ltmask);
            if (pos < CAP) {
                cval[wid][pos] = v[e];
                cidx[wid][pos] = ((e >> 2) * 64 + lane) * 4 + (e & 3);
            }
        }
        cnt += __popcll(m);
    }
    cnt = min(cnt, CAP);

    // exact 25-way select, (value,index) lexicographic == lax.top_k set
    float ssum = 0.f;
    for (int it = 0; it < NK; ++it) {
        float bv = FLT_MAX; int bi = NB; int bp = -1;
        for (int r = lane; r < cnt; r += 64) {
            float cv = cval[wid][r]; int ci = cidx[wid][r];
            if (cv < bv || (cv == bv && ci < bi)) { bv = cv; bi = ci; bp = r; }
        }
#pragma unroll
        for (int off = 32; off; off >>= 1) {
            float ov = __shfl_xor(bv, off);
            int   oi = __shfl_xor(bi, off);
            int   op = __shfl_xor(bp, off);
            if (ov < bv || (ov == bv && oi < bi)) { bv = ov; bi = oi; bp = op; }
        }
        if (lane == 0) {
            idxk[row * NK + it] = bi;
            dk[row * NK + it]   = bv;
            cval[wid][bp] = FLT_MAX;             // same-wave DS ordering ok
        }
        ssum += sqrtf(bv + EPSF);                // bv uniform across lanes
    }
    if (lane == 0) sigma[row] = ssum * (1.0f / NK);
}

// ---------------------------------------------------------------- sparse P rows
__global__ __launch_bounds__(64) void buildp_kernel(const int* __restrict__ idxk,
                                                    const float* __restrict__ dk,
                                                    const float* __restrict__ sigma,
                                                    const int* __restrict__ labels,
                                                    float* __restrict__ pval) {
    int row  = blockIdx.x;
    int lane = threadIdx.x;
    float w = 0.f;
    if (lane < NK) {
        int j = idxk[row * NK + lane];
        bool mut = false;
        for (int n = 0; n < NK; ++n) mut |= (idxk[j * NK + n] == row);
        bool dir = labels[row] <= labels[j];
        float sij = sigma[row] * sigma[j] + EPSF;
        w = (mut && dir) ? expf(-dk[row * NK + lane] / sij) : 0.f;
        if (j == row) w += 1.f;
    }
    float rs = w;
#pragma unroll
    for (int off = 32; off; off >>= 1) rs += __shfl_down(rs, off);
    rs = __shfl(rs, 0);
    if (lane < NK) pval[row * NK + lane] = w / (rs + EPSF);
}

// ---------------------------------------------------------------- init out
__global__ void init_kernel(float* __restrict__ out) { out[0] = 0.f; }

// ---------------------------------------------------------------- sparse 3-hop loss
__global__ __launch_bounds__(256) void loss_kernel(const float* __restrict__ scores,
                                                   const int* __restrict__ idxk,
                                                   const float* __restrict__ pval,
                                                   float* __restrict__ out) {
    int i = blockIdx.x;
    __shared__ float sh_s[NB];
    __shared__ float sh_p[NK];
    __shared__ int   sh_j[NK];
    __shared__ float red[4];
    int tid = threadIdx.x;
    for (int t = tid; t < NB / 4; t += 256) {
        float4 v = ((const float4*)scores)[t];
        sh_s[4 * t + 0] = v.x; sh_s[4 * t + 1] = v.y;
        sh_s[4 * t + 2] = v.z; sh_s[4 * t + 3] = v.w;
    }
    if (tid < NK) { sh_p[tid] = pval[i * NK + tid]; sh_j[tid] = idxk[i * NK + tid]; }
    __syncthreads();
    float si = sh_s[i];
    float acc = 0.f;
    if (tid < NK) acc += sh_p[tid] * fmaxf(si - sh_s[sh_j[tid]], 0.f);
    for (int pair = tid; pair < NK * NK; pair += 256) {
        int m = pair / NK, n = pair % NK;
        int   j   = sh_j[m];
        float pij = sh_p[m];
        int   q   = idxk[j * NK + n];
        float pjn = pval[j * NK + n];
        float pp  = pij * pjn;
        acc += 0.5f * pp * fmaxf(si - sh_s[q], 0.f);
        const int*   qi = idxk + q * NK;
        const float* qp = pval + q * NK;
        float s3 = 0.f;
        for (int r = 0; r < NK; ++r)
            s3 += qp[r] * fmaxf(si - sh_s[qi[r]], 0.f);
        acc += (1.f / 3.f) * pp * s3;
    }
#pragma unroll
    for (int off = 32; off; off >>= 1) acc += __shfl_down(acc, off);
    if ((tid & 63) == 0) red[tid >> 6] = acc;
    __syncthreads();
    if (tid == 0) atomicAdd(out, (red[0] + red[1] + red[2] + red[3]) * (1.0f / NB));
}

// ---------------------------------------------------------------- launch
extern "C" void kernel_launch(void* const* d_in, const int* in_sizes, int n_in,
                              void* d_out, int out_size, void* d_ws, size_t ws_size,
                              hipStream_t stream) {
    const float* features = (const float*)d_in[0];
    const float* scores   = (const float*)d_in[1];
    const int*   labels   = (const int*)d_in[2];
    float* out = (float*)d_out;

    char* ws = (char*)d_ws;
    size_t off = 0;
    float* dist  = (float*)(ws + off); off += (size_t)NB * NB * 4;
    short* fhl   = (short*)(ws + off); off += (size_t)NB * 512 * 2;
    float* sq    = (float*)(ws + off); off += (size_t)NB * 4;
    int*   idxk  = (int*)  (ws + off); off += (size_t)NB * NK * 4;
    float* dk    = (float*)(ws + off); off += (size_t)NB * NK * 4;
    float* sigma = (float*)(ws + off); off += (size_t)NB * 4;
    float* pval  = (float*)(ws + off);

    init_kernel<<<1, 1, 0, stream>>>(out);
    prep_kernel<<<NB, 64, 0, stream>>>(features, fhl, sq);
    gram_kernel<<<(NB / BM) * (NB / BM), 256, 0, stream>>>(fhl, sq, dist);
    topk3_kernel<<<NB / 4, 256, 0, stream>>>(dist, idxk, dk, sigma);
    buildp_kernel<<<NB, 64, 0, stream>>>(idxk, dk, sigma, labels, pval);
    loss_kernel<<<NB, 256, 0, stream>>>(scores, idxk, pval, out);
}